// Round 1
// 496.104 us; speedup vs baseline: 1.0836x; 1.0836x over previous
//
#include <hip/hip_runtime.h>
#include <hip/hip_fp16.h>

// ---------------------------------------------------------------------------
// GCN 3-layer forward. fp32 accumulate; fp16 message buffer G.
// R4: fp16 G. R6: fused scans. R9: 16B/lane agg gather (cache-BW ceiling).
// R10: fat kernel = gemm layer-0 + fill phase-0.
// R11 (this round): VALU fp32 GEMM -> MFMA fp16 GEMM (mfma_f32_16x16x32_f16,
//   fp32 acc). W pre-transposed+fp16-converted once (fused into deg kernel).
//   hbuf fp32 -> fp16 (free: next gemm rounds input to fp16 anyway; halves
//   inter-layer traffic). LDS tiles [rows][64+8] halves: 144B row stride ->
//   uniform 8 lanes/bank-group on ds_read_b128 (conflict-free per m136).
// ---------------------------------------------------------------------------

typedef _Float16 f16;
typedef __attribute__((ext_vector_type(8))) _Float16 f16x8;
typedef __attribute__((ext_vector_type(4))) _Float16 f16x4;
typedef __attribute__((ext_vector_type(4))) float f32x4;

// deg (atomic histogram) + W fp16-transpose prep fused (blocks >= gE).
__global__ __launch_bounds__(256)
void deg_prep_kernel(const int* __restrict__ dst, int* __restrict__ cnt, int E,
                     int gE, const float* __restrict__ W0,
                     const float* __restrict__ W1, const float* __restrict__ W2,
                     __half* __restrict__ w0t, __half* __restrict__ w1t,
                     __half* __restrict__ w2t) {
  int b = blockIdx.x;
  if (b < gE) {
    int e = b * 256 + threadIdx.x;
    if (e < E) atomicAdd(&cnt[dst[e]], 1);
  } else {
    int i = (b - gE) * 256 + threadIdx.x;
    if (i < 16384) {
      int n = i >> 7, k = i & 127;
      w0t[i] = __float2half_rn(W0[k * 128 + n]);           // w0t[n][k] = W0[k][n]
    } else if (i < 32768) {
      int j = i - 16384;
      int n = j >> 7, k = j & 127;
      w1t[j] = __float2half_rn(W1[k * 128 + n]);
    } else if (i < 38912) {
      int j = i - 32768;
      int n = j >> 7, k = j & 127;                          // n in [0,48)
      w2t[j] = (n < 40) ? __float2half_rn(W2[k * 40 + n]) : __float2half_rn(0.f);
    }
  }
}

// Per-block partial sums of cnt (2048/block) + dinv computed on the fly.
__global__ __launch_bounds__(256)
void scan_partial_dinv_kernel(const int* __restrict__ cnt, int* __restrict__ blocksums,
                              float* __restrict__ dinv, int n) {
  __shared__ int sm[256];
  int base = blockIdx.x * 2048 + threadIdx.x * 8;
  int s = 0;
#pragma unroll
  for (int i = 0; i < 8; ++i) {
    int idx = base + i;
    if (idx < n) {
      int c = cnt[idx];
      s += c;
      dinv[idx] = 1.0f / sqrtf((float)c + 1.0f);
    }
  }
  sm[threadIdx.x] = s;
  __syncthreads();
#pragma unroll
  for (int off = 128; off > 0; off >>= 1) {
    if (threadIdx.x < off) sm[threadIdx.x] += sm[threadIdx.x + off];
    __syncthreads();
  }
  if (threadIdx.x == 0) blocksums[blockIdx.x] = sm[0];
}

// Intra-block exclusive scan + internal scan of blocksums -> rowptr, woff.
__global__ __launch_bounds__(256)
void scan_write_kernel(const int* __restrict__ cnt, const int* __restrict__ blocksums,
                       int* __restrict__ rowptr, int* __restrict__ woff,
                       int n, int E, int nb) {
  __shared__ int sm[256];
  __shared__ int bs[256];
  int t = threadIdx.x;
  if (t < nb) bs[t] = blocksums[t];
  __syncthreads();
  if (t == 0) {
    int run = 0;
    for (int i = 0; i < nb; ++i) {
      int v = bs[i];
      bs[i] = run;
      run += v;
    }
  }
  int base = blockIdx.x * 2048 + t * 8;
  int v[8];
  int s = 0;
#pragma unroll
  for (int i = 0; i < 8; ++i) {
    int idx = base + i;
    v[i] = (idx < n) ? cnt[idx] : 0;
    s += v[i];
  }
  sm[t] = s;
  __syncthreads();
#pragma unroll
  for (int off = 1; off < 256; off <<= 1) {
    int u = (t >= off) ? sm[t - off] : 0;
    __syncthreads();
    sm[t] += u;
    __syncthreads();
  }
  int p = bs[blockIdx.x] + (t ? sm[t - 1] : 0);
#pragma unroll
  for (int i = 0; i < 8; ++i) {
    int idx = base + i;
    if (idx < n) {
      rowptr[idx] = p;
      woff[idx] = p;
      p += v[i];
    }
  }
  if (blockIdx.x == 0 && t == 0) rowptr[n] = E;
}

// fill body: edges with dst in [lo,hi) scatter src into col via woff.
__device__ __forceinline__
void fill_body(const int* __restrict__ src, const int* __restrict__ dst,
               int* __restrict__ woff, int* __restrict__ col, int E,
               int lo, int hi, int blk) {
  int e = blk * 256 + threadIdx.x;
  if (e < E) {
    int d = dst[e];
    if (d >= lo && d < hi) {
      int pos = atomicAdd(&woff[d], 1);
      col[pos] = src[e];
    }
  }
}

__global__ __launch_bounds__(256)
void fill_phase_kernel(const int* __restrict__ src, const int* __restrict__ dst,
                       int* __restrict__ woff, int* __restrict__ col, int E,
                       int lo, int hi) {
  fill_body(src, dst, woff, col, E, lo, hi, blockIdx.x);
}

// ---------------------------------------------------------------------------
// MFMA fp16 GEMM: G[r][c] = fp16(dinv[r] * sum_k X[r][k] * W[k][c]).
// M=128/block, N=128, K=128 (BK=64 chunks). 4 waves, each 32 rows x 128 cols
// = 2x8 tiles of 16x16, K=32 per mfma step.
// Fragment layout (mfma_f32_16x16x32_f16):
//   A: lane holds X[lane&15][(lane>>4)*8 + i]      (16B contiguous ds_read)
//   B: lane holds W[(lane>>4)*8 + i][lane&15]      -> stage W TRANSPOSED [n][k]
//   D: lane holds D[(lane>>4)*4 + i][lane&15]
// LDS row stride 72 halves (144B): bank group = (row + kgrp) & 7 -> uniform
// 8 lanes/group on b128 (minimum), conflict-free.
// ---------------------------------------------------------------------------
template <typename TIN>
__device__ __forceinline__
void mfma_gemm128_body(const TIN* __restrict__ X, const __half* __restrict__ Wt,
                       const float* __restrict__ dinv, __half* __restrict__ G,
                       int nrows, int blk, f16 (*xs)[72], f16 (*ws)[72]) {
  const int tid = threadIdx.x;
  const int wave = tid >> 6;
  const int lane = tid & 63;
  const int mrow = lane & 15;
  const int kg = lane >> 4;
  const int row0 = blk * 128;

  f32x4 acc[2][8];
#pragma unroll
  for (int i = 0; i < 2; ++i)
#pragma unroll
    for (int j = 0; j < 8; ++j) acc[i][j] = (f32x4){0.f, 0.f, 0.f, 0.f};

  for (int k0 = 0; k0 < 128; k0 += 64) {
    // ---- stage X chunk (128 rows x 64 k) ----
    if constexpr (sizeof(TIN) == 4) {
#pragma unroll
      for (int t = tid; t < 2048; t += 256) {
        int r = t >> 4;
        int kk = (t & 15) * 4;
        float4 v = make_float4(0.f, 0.f, 0.f, 0.f);
        if (row0 + r < nrows)
          v = *(const float4*)((const float*)X + (size_t)(row0 + r) * 128 + k0 + kk);
        f16x4 hv = {(f16)v.x, (f16)v.y, (f16)v.z, (f16)v.w};
        *(f16x4*)&xs[r][kk] = hv;
      }
    } else {
#pragma unroll
      for (int t = tid; t < 1024; t += 256) {
        int r = t >> 3;
        int kk = (t & 7) * 8;
        f16x8 v = (f16x8){0, 0, 0, 0, 0, 0, 0, 0};
        if (row0 + r < nrows)
          v = *(const f16x8*)((const f16*)X + (size_t)(row0 + r) * 128 + k0 + kk);
        *(f16x8*)&xs[r][kk] = v;
      }
    }
    // ---- stage Wt chunk (128 n-rows x 64 k) ----
#pragma unroll
    for (int t = tid; t < 1024; t += 256) {
      int r = t >> 3;
      int kk = (t & 7) * 8;
      *(f16x8*)&ws[r][kk] =
          *(const f16x8*)((const f16*)Wt + (size_t)r * 128 + k0 + kk);
    }
    __syncthreads();
#pragma unroll
    for (int ks = 0; ks < 64; ks += 32) {
      f16x8 a0 = *(const f16x8*)&xs[wave * 32 + mrow][ks + kg * 8];
      f16x8 a1 = *(const f16x8*)&xs[wave * 32 + 16 + mrow][ks + kg * 8];
#pragma unroll
      for (int nt = 0; nt < 8; ++nt) {
        f16x8 b = *(const f16x8*)&ws[nt * 16 + mrow][ks + kg * 8];
        acc[0][nt] = __builtin_amdgcn_mfma_f32_16x16x32_f16(a0, b, acc[0][nt], 0, 0, 0);
        acc[1][nt] = __builtin_amdgcn_mfma_f32_16x16x32_f16(a1, b, acc[1][nt], 0, 0, 0);
      }
    }
    __syncthreads();
  }
  // ---- epilogue: D row = (lane>>4)*4+i, col = lane&15 within tile ----
#pragma unroll
  for (int mt = 0; mt < 2; ++mt) {
    int rbase = row0 + wave * 32 + mt * 16 + kg * 4;
#pragma unroll
    for (int i = 0; i < 4; ++i) {
      int grow = rbase + i;
      if (grow < nrows) {
        float s = dinv[grow];
        __half* gp = G + (size_t)grow * 128 + mrow;
#pragma unroll
        for (int nt = 0; nt < 8; ++nt)
          gp[nt * 16] = __float2half_rn(s * acc[mt][nt][i]);
      }
    }
  }
}

__global__ __launch_bounds__(256)
void mfma_gemm128_kernel(const __half* __restrict__ X, const __half* __restrict__ Wt,
                         const float* __restrict__ dinv, __half* __restrict__ G,
                         int nrows) {
  __shared__ f16 xs[128][72];
  __shared__ f16 ws[128][72];
  mfma_gemm128_body<__half>(X, Wt, dinv, G, nrows, blockIdx.x, xs, ws);
}

// Fat kernel: blocks [0,gGemm) run MFMA gemm layer-0; the rest run fill phase-0.
__global__ __launch_bounds__(256)
void gemm128_fill_kernel(const float* __restrict__ X, const __half* __restrict__ Wt,
                         const float* __restrict__ dinv, __half* __restrict__ G,
                         int nrows, int gGemm,
                         const int* __restrict__ src, const int* __restrict__ dst,
                         int* __restrict__ woff, int* __restrict__ col, int E,
                         int lo, int hi) {
  __shared__ f16 xs[128][72];
  __shared__ f16 ws[128][72];
  if ((int)blockIdx.x < gGemm) {
    mfma_gemm128_body<float>(X, Wt, dinv, G, nrows, blockIdx.x, xs, ws);
  } else {
    fill_body(src, dst, woff, col, E, lo, hi, blockIdx.x - gGemm);
  }
}

// Output layer: N=40 (padded to 48 = 3 n-tiles; Wt2 rows 40..47 are zeros).
__global__ __launch_bounds__(256)
void mfma_gemm48_kernel(const __half* __restrict__ X, const __half* __restrict__ Wt,
                        const float* __restrict__ dinv, __half* __restrict__ G,
                        int nrows) {
  __shared__ f16 xs[128][72];
  __shared__ f16 ws[48][72];
  const int tid = threadIdx.x;
  const int wave = tid >> 6;
  const int lane = tid & 63;
  const int mrow = lane & 15;
  const int kg = lane >> 4;
  const int row0 = blockIdx.x * 128;

  f32x4 acc[2][3];
#pragma unroll
  for (int i = 0; i < 2; ++i)
#pragma unroll
    for (int j = 0; j < 3; ++j) acc[i][j] = (f32x4){0.f, 0.f, 0.f, 0.f};

  for (int k0 = 0; k0 < 128; k0 += 64) {
#pragma unroll
    for (int t = tid; t < 1024; t += 256) {
      int r = t >> 3;
      int kk = (t & 7) * 8;
      f16x8 v = (f16x8){0, 0, 0, 0, 0, 0, 0, 0};
      if (row0 + r < nrows)
        v = *(const f16x8*)((const f16*)X + (size_t)(row0 + r) * 128 + k0 + kk);
      *(f16x8*)&xs[r][kk] = v;
    }
#pragma unroll
    for (int t = tid; t < 384; t += 256) {
      int r = t >> 3;
      int kk = (t & 7) * 8;
      *(f16x8*)&ws[r][kk] =
          *(const f16x8*)((const f16*)Wt + (size_t)r * 128 + k0 + kk);
    }
    __syncthreads();
#pragma unroll
    for (int ks = 0; ks < 64; ks += 32) {
      f16x8 a0 = *(const f16x8*)&xs[wave * 32 + mrow][ks + kg * 8];
      f16x8 a1 = *(const f16x8*)&xs[wave * 32 + 16 + mrow][ks + kg * 8];
#pragma unroll
      for (int nt = 0; nt < 3; ++nt) {
        f16x8 b = *(const f16x8*)&ws[nt * 16 + mrow][ks + kg * 8];
        acc[0][nt] = __builtin_amdgcn_mfma_f32_16x16x32_f16(a0, b, acc[0][nt], 0, 0, 0);
        acc[1][nt] = __builtin_amdgcn_mfma_f32_16x16x32_f16(a1, b, acc[1][nt], 0, 0, 0);
      }
    }
    __syncthreads();
  }
#pragma unroll
  for (int mt = 0; mt < 2; ++mt) {
    int rbase = row0 + wave * 32 + mt * 16 + kg * 4;
#pragma unroll
    for (int i = 0; i < 4; ++i) {
      int grow = rbase + i;
      if (grow < nrows) {
        float s = dinv[grow];
#pragma unroll
        for (int nt = 0; nt < 3; ++nt) {
          int c = nt * 16 + mrow;
          if (c < 40)
            G[(size_t)grow * 40 + c] = __float2half_rn(s * acc[mt][nt][i]);
        }
      }
    }
  }
}

// M=128 aggregate, 16B/lane: 16 lanes cover one 256B G row (4x64B coalesced).
// TOUT = __half (feeding next MFMA gemm: fp16 store is free precision-wise)
// or float (unused now, kept for generality).
template <bool RELU, typename TOUT>
__global__ __launch_bounds__(256)
void aggregate128_kernel(const __half* __restrict__ G, const int* __restrict__ rowptr,
                         const int* __restrict__ col, const float* __restrict__ dinv,
                         const float* __restrict__ bias, TOUT* __restrict__ out,
                         int n) {
  int wid = threadIdx.x >> 6;
  int lane = threadIdx.x & 63;
  int node = blockIdx.x * 4 + wid;
  if (node >= n) return;

  int sub = lane >> 4;
  int c = lane & 15;
  const float4* g4 = (const float4*)G;  // row stride = 16 float4

  int e = rowptr[node];
  int end = rowptr[node + 1];
  float di = dinv[node];

  float a0 = 0.f, a1 = 0.f, a2 = 0.f, a3 = 0.f,
        a4 = 0.f, a5 = 0.f, a6 = 0.f, a7 = 0.f;

  auto accum = [&](float4 raw) {
    const __half2* h = (const __half2*)&raw;
    float2 f0 = __half22float2(h[0]);
    float2 f1 = __half22float2(h[1]);
    float2 f2 = __half22float2(h[2]);
    float2 f3 = __half22float2(h[3]);
    a0 += f0.x; a1 += f0.y; a2 += f1.x; a3 += f1.y;
    a4 += f2.x; a5 += f2.y; a6 += f3.x; a7 += f3.y;
  };

  if (sub == 0) accum(g4[(size_t)node * 16 + c]);  // self-loop once

  int base = e;
  for (; base + 16 <= end; base += 16) {
    float4 r0 = g4[(size_t)col[base + sub] * 16 + c];
    float4 r1 = g4[(size_t)col[base + sub + 4] * 16 + c];
    float4 r2 = g4[(size_t)col[base + sub + 8] * 16 + c];
    float4 r3 = g4[(size_t)col[base + sub + 12] * 16 + c];
    accum(r0);
    accum(r1);
    accum(r2);
    accum(r3);
  }
  for (; base + 4 <= end; base += 4) {
    accum(g4[(size_t)col[base + sub] * 16 + c]);
  }
  if (base + sub < end) {
    accum(g4[(size_t)col[base + sub] * 16 + c]);
  }

  a0 += __shfl_xor(a0, 16); a1 += __shfl_xor(a1, 16);
  a2 += __shfl_xor(a2, 16); a3 += __shfl_xor(a3, 16);
  a4 += __shfl_xor(a4, 16); a5 += __shfl_xor(a5, 16);
  a6 += __shfl_xor(a6, 16); a7 += __shfl_xor(a7, 16);
  a0 += __shfl_xor(a0, 32); a1 += __shfl_xor(a1, 32);
  a2 += __shfl_xor(a2, 32); a3 += __shfl_xor(a3, 32);
  a4 += __shfl_xor(a4, 32); a5 += __shfl_xor(a5, 32);
  a6 += __shfl_xor(a6, 32); a7 += __shfl_xor(a7, 32);

  if (sub == 0) {
    const float4* b4 = (const float4*)bias;
    float4 bb0 = b4[c * 2];
    float4 bb1 = b4[c * 2 + 1];
    float o[8] = {di * a0 + bb0.x, di * a1 + bb0.y, di * a2 + bb0.z,
                  di * a3 + bb0.w, di * a4 + bb1.x, di * a5 + bb1.y,
                  di * a6 + bb1.z, di * a7 + bb1.w};
    if (RELU) {
#pragma unroll
      for (int j = 0; j < 8; ++j) o[j] = fmaxf(o[j], 0.f);
    }
    if constexpr (sizeof(TOUT) == 2) {
      union { __half2 h[4]; float4 f; } u;
      u.h[0] = __floats2half2_rn(o[0], o[1]);
      u.h[1] = __floats2half2_rn(o[2], o[3]);
      u.h[2] = __floats2half2_rn(o[4], o[5]);
      u.h[3] = __floats2half2_rn(o[6], o[7]);
      *(float4*)((__half*)out + (size_t)node * 128 + c * 8) = u.f;
    } else {
      float4* op = (float4*)((float*)out + (size_t)node * 128 + c * 8);
      op[0] = make_float4(o[0], o[1], o[2], o[3]);
      op[1] = make_float4(o[4], o[5], o[6], o[7]);
    }
  }
}

// M=40 aggregate, 6-way lane-split.
__global__ __launch_bounds__(256)
void aggregate40_kernel(const __half* __restrict__ G, const int* __restrict__ rowptr,
                        const int* __restrict__ col, const float* __restrict__ dinv,
                        const float* __restrict__ bias, float* __restrict__ out,
                        int n) {
  int wid = threadIdx.x >> 6;
  int lane = threadIdx.x & 63;
  int node = blockIdx.x * 4 + wid;
  if (node >= n) return;

  int sub = lane / 10;
  int c = lane % 10;
  const float2* g2 = (const float2*)G;

  int e = rowptr[node];
  int end = rowptr[node + 1];
  float di = dinv[node];

  float ax = 0.f, ay = 0.f, az = 0.f, aw = 0.f;
  if (sub == 0) {
    float2 raw = g2[(size_t)node * 10 + c];
    float2 f0 = __half22float2(*(const __half2*)&raw.x);
    float2 f1 = __half22float2(*(const __half2*)&raw.y);
    ax = f0.x; ay = f0.y; az = f1.x; aw = f1.y;
  }

  if (sub < 6) {
    int i = e + sub;
    for (; i + 11 < end; i += 12) {
      int s0 = col[i];
      int s1 = col[i + 6];
      float2 r0 = g2[(size_t)s0 * 10 + c];
      float2 r1 = g2[(size_t)s1 * 10 + c];
      float2 f0 = __half22float2(*(const __half2*)&r0.x);
      float2 f1 = __half22float2(*(const __half2*)&r0.y);
      float2 f2 = __half22float2(*(const __half2*)&r1.x);
      float2 f3 = __half22float2(*(const __half2*)&r1.y);
      ax += f0.x + f2.x; ay += f0.y + f2.y;
      az += f1.x + f3.x; aw += f1.y + f3.y;
    }
    for (; i < end; i += 6) {
      int s0 = col[i];
      float2 r0 = g2[(size_t)s0 * 10 + c];
      float2 f0 = __half22float2(*(const __half2*)&r0.x);
      float2 f1 = __half22float2(*(const __half2*)&r0.y);
      ax += f0.x; ay += f0.y; az += f1.x; aw += f1.y;
    }
  }

  float bx = __shfl(ax, lane + 30), by = __shfl(ay, lane + 30),
        bz = __shfl(az, lane + 30), bw = __shfl(aw, lane + 30);
  ax += bx; ay += by; az += bz; aw += bw;
  float c1x = __shfl(ax, lane + 10), c1y = __shfl(ay, lane + 10),
        c1z = __shfl(az, lane + 10), c1w = __shfl(aw, lane + 10);
  float c2x = __shfl(ax, lane + 20), c2y = __shfl(ay, lane + 20),
        c2z = __shfl(az, lane + 20), c2w = __shfl(aw, lane + 20);

  if (sub == 0) {
    float sx = ax + c1x + c2x;
    float sy = ay + c1y + c2y;
    float sz = az + c1z + c2z;
    float sw = aw + c1w + c2w;
    float4 bb = ((const float4*)bias)[c];
    float4 o = make_float4(di * sx + bb.x, di * sy + bb.y, di * sz + bb.z,
                           di * sw + bb.w);
    ((float4*)out)[(size_t)node * 10 + c] = o;
  }
}

extern "C" void kernel_launch(void* const* d_in, const int* in_sizes, int n_in,
                              void* d_out, int out_size, void* d_ws, size_t ws_size,
                              hipStream_t stream) {
  const float* x = (const float*)d_in[0];
  const float* W0 = (const float*)d_in[1];
  const float* b0 = (const float*)d_in[2];
  const float* W1 = (const float*)d_in[3];
  const float* b1 = (const float*)d_in[4];
  const float* W2 = (const float*)d_in[5];
  const float* b2 = (const float*)d_in[6];
  const int* ei = (const int*)d_in[7];

  const int N = in_sizes[0] / 128;
  const int E = in_sizes[7] / 2;
  const int* src = ei;
  const int* dst = ei + E;

  char* w = (char*)d_ws;
  size_t off = 0;
  auto alloc = [&](size_t bytes) -> void* {
    void* p = w + off;
    off = (off + bytes + 255) & ~(size_t)255;
    return p;
  };
  int* cnt = (int*)alloc((size_t)N * 4);
  float* dinv = (float*)alloc((size_t)N * 4);
  int* rowptr = (int*)alloc((size_t)(N + 1) * 4);
  int* woff = (int*)alloc((size_t)N * 4);
  int* col = (int*)alloc((size_t)E * 4);
  int* blocksums = (int*)alloc(4096 * 4);
  __half* gbuf = (__half*)alloc((size_t)N * 128 * 2);
  __half* hbuf = (__half*)alloc((size_t)N * 128 * 2);
  __half* w0t = (__half*)alloc(128 * 128 * 2);
  __half* w1t = (__half*)alloc(128 * 128 * 2);
  __half* w2t = (__half*)alloc(48 * 128 * 2);
  (void)ws_size;

  hipMemsetAsync(cnt, 0, (size_t)N * 4, stream);

  dim3 blk(256);
  int gE = (E + 255) / 256;
  int gW = (38912 + 255) / 256;
  int nScanBlocks = (N + 2047) / 2048;

  deg_prep_kernel<<<gE + gW, blk, 0, stream>>>(dst, cnt, E, gE, W0, W1, W2,
                                               w0t, w1t, w2t);
  scan_partial_dinv_kernel<<<nScanBlocks, blk, 0, stream>>>(cnt, blocksums, dinv, N);
  scan_write_kernel<<<nScanBlocks, blk, 0, stream>>>(cnt, blocksums, rowptr, woff, N, E,
                                                     nScanBlocks);

  int gGemm = (N + 127) / 128;
  int gAgg = (N + 3) / 4;
  int half = (N + 1) / 2;

  // FAT: MFMA gemm layer-0 + fill phase 0 (dst in [0, half))
  gemm128_fill_kernel<<<gGemm + gE, blk, 0, stream>>>(x, w0t, dinv, gbuf, N, gGemm,
                                                      src, dst, woff, col, E, 0, half);
  // fill phase 1 (dst in [half, N))
  fill_phase_kernel<<<gE, blk, 0, stream>>>(src, dst, woff, col, E, half, N);

  aggregate128_kernel<true, __half><<<gAgg, blk, 0, stream>>>(gbuf, rowptr, col, dinv,
                                                              b0, hbuf, N);
  mfma_gemm128_kernel<<<gGemm, blk, 0, stream>>>(hbuf, w1t, dinv, gbuf, N);
  aggregate128_kernel<true, __half><<<gAgg, blk, 0, stream>>>(gbuf, rowptr, col, dinv,
                                                              b1, hbuf, N);
  mfma_gemm48_kernel<<<gGemm, blk, 0, stream>>>(hbuf, w2t, dinv, gbuf, N);
  aggregate40_kernel<<<gAgg, blk, 0, stream>>>(gbuf, rowptr, col, dinv, b2,
                                               (float*)d_out, N);
}

// Round 2
// 358.277 us; speedup vs baseline: 1.5004x; 1.3847x over previous
//
#include <hip/hip_runtime.h>
#include <hip/hip_fp16.h>

// ---------------------------------------------------------------------------
// GCN 3-layer forward. fp32 accumulate; fp16 message buffer G.
// R4: fp16 G. R9: 16B/lane agg gather (cache-BW ceiling). R11: MFMA fp16
//   GEMMs (mfma_f32_16x16x32_f16), fp16 hbuf, W pre-transposed once.
// R12 (this round): bucketed CSR build replaces {deg atomics, 2 scans,
//   2 fill passes}. K1 partitions edges into 391 buckets (dst>>8) with
//   per-block LDS histograms + chunk reservations (153K global atomics vs
//   3.2M random). K2 finalizes each bucket entirely in LDS (counts, scan,
//   rowptr, dinv, col scatter with LDS atomics -> contiguous 16KB segment)
//   fused with MFMA gemm layer-0. GEMMs no longer pre-scale by dinv[row];
//   aggregates weight each gathered row by dinv[col] (add->fma, free).
// ---------------------------------------------------------------------------

#define CAP 8192     // per-bucket capacity (mean 4096, +64 sigma)
#define NBMAX 512

typedef _Float16 f16;
typedef __attribute__((ext_vector_type(8))) _Float16 f16x8;
typedef __attribute__((ext_vector_type(4))) _Float16 f16x4;
typedef __attribute__((ext_vector_type(4))) float f32x4;

// ---------------------------------------------------------------------------
// K1: bucket partition (blocks < gP1) + W fp16-transpose prep (rest).
// Packed entry: (src << 8) | (dst & 255); bucket = dst >> 8.
// ---------------------------------------------------------------------------
__global__ __launch_bounds__(256)
void bucket_prep_kernel(const int* __restrict__ src, const int* __restrict__ dst,
                        int E, int gP1, int NB,
                        int* __restrict__ bucket_cnt, unsigned* __restrict__ bucketbuf,
                        const float* __restrict__ W0, const float* __restrict__ W1,
                        const float* __restrict__ W2,
                        __half* __restrict__ w0t, __half* __restrict__ w1t,
                        __half* __restrict__ w2t) {
  int b = blockIdx.x;
  if (b < gP1) {
    __shared__ int hist[NBMAX];
    __shared__ int cbase[NBMAX];
    int tid = threadIdx.x;
    for (int i = tid; i < NB; i += 256) hist[i] = 0;
    __syncthreads();
    int e0 = b * 4096;
    int eend = min(e0 + 4096, E);
    for (int e = e0 + tid; e < eend; e += 256)
      atomicAdd(&hist[((unsigned)dst[e]) >> 8], 1);
    __syncthreads();
    for (int i = tid; i < NB; i += 256) {
      int h = hist[i];
      cbase[i] = h ? atomicAdd(&bucket_cnt[i], h) : 0;
    }
    __syncthreads();
    for (int i = tid; i < NB; i += 256) hist[i] = 0;
    __syncthreads();
    for (int e = e0 + tid; e < eend; e += 256) {
      int d = dst[e];
      int s = src[e];
      int bk = ((unsigned)d) >> 8;
      int idx = cbase[bk] + atomicAdd(&hist[bk], 1);
      if (idx < CAP)
        bucketbuf[(size_t)bk * CAP + idx] = (((unsigned)s) << 8) | (unsigned)(d & 255);
    }
  } else {
    int i = (b - gP1) * 256 + threadIdx.x;
    if (i < 16384) {
      int n = i >> 7, k = i & 127;
      w0t[i] = __float2half_rn(W0[k * 128 + n]);           // w0t[n][k] = W0[k][n]
    } else if (i < 32768) {
      int j = i - 16384;
      int n = j >> 7, k = j & 127;
      w1t[j] = __float2half_rn(W1[k * 128 + n]);
    } else if (i < 38912) {
      int j = i - 32768;
      int n = j >> 7, k = j & 127;                          // n in [0,48)
      w2t[j] = (n < 40) ? __float2half_rn(W2[k * 40 + n]) : __float2half_rn(0.f);
    }
  }
}

// ---------------------------------------------------------------------------
// Phase 2 (per bucket, fused into K2): counts, scan, rowptr, dinv, col.
// Entire bucket (<=8192 edges, 256 nodes) processed in LDS; col writes go to
// a contiguous [base, base+cnt) segment (~16KB, L2-local).
// ---------------------------------------------------------------------------
struct P2Shared {
  unsigned plist[CAP];   // 32 KB
  int cnts[256];
  int sm[256];
};

__device__ __forceinline__
void phase2_body(const unsigned* __restrict__ bucketbuf, const int* __restrict__ bucket_cnt,
                 int* __restrict__ rowptr, float* __restrict__ dinv,
                 int* __restrict__ col, int N, int E, int NB, int b, P2Shared& sh) {
  int tid = threadIdx.x;
  int cnt_b = min(bucket_cnt[b], CAP);

  // base = exclusive prefix over bucket_cnt[0..b)  (<=2 strided loads + reduce)
  int part = 0;
  for (int i = tid; i < b; i += 256) part += bucket_cnt[i];
  sh.sm[tid] = part;
  __syncthreads();
#pragma unroll
  for (int off = 128; off > 0; off >>= 1) {
    if (tid < off) sh.sm[tid] += sh.sm[tid + off];
    __syncthreads();
  }
  int base = sh.sm[0];
  __syncthreads();

  // stage bucket list; per-node counts via LDS atomics
  for (int i = tid; i < cnt_b; i += 256)
    sh.plist[i] = bucketbuf[(size_t)b * CAP + i];
  sh.cnts[tid] = 0;
  __syncthreads();
  for (int i = tid; i < cnt_b; i += 256)
    atomicAdd(&sh.cnts[sh.plist[i] & 255u], 1);
  __syncthreads();

  // exclusive scan of 256 counts
  int myc = sh.cnts[tid];
  sh.sm[tid] = myc;
  __syncthreads();
#pragma unroll
  for (int off = 1; off < 256; off <<= 1) {
    int u = (tid >= off) ? sh.sm[tid - off] : 0;
    __syncthreads();
    sh.sm[tid] += u;
    __syncthreads();
  }
  int exc = sh.sm[tid] - myc;

  int n = (b << 8) + tid;
  if (n < N) {
    rowptr[n] = base + exc;
    dinv[n] = 1.0f / sqrtf((float)myc + 1.0f);
  }
  if (b == NB - 1 && tid == 0) rowptr[N] = E;
  __syncthreads();

  // woff in LDS (overwrite cnts), scatter col with LDS atomics
  sh.cnts[tid] = base + exc;
  __syncthreads();
  for (int i = tid; i < cnt_b; i += 256) {
    unsigned p = sh.plist[i];
    int pos = atomicAdd(&sh.cnts[p & 255u], 1);
    col[pos] = (int)(p >> 8);
  }
}

// ---------------------------------------------------------------------------
// MFMA fp16 GEMM: G[r][c] = fp16(sum_k X[r][k] * W[k][c]).  (no dinv scale)
// M=128/block, N=128, K=128 (BK=64 chunks). 4 waves, 2x8 tiles of 16x16.
// LDS row stride 72 halves (144B) -> conflict-free b128 reads.
// ---------------------------------------------------------------------------
template <typename TIN>
__device__ __forceinline__
void mfma_gemm128_body(const TIN* __restrict__ X, const __half* __restrict__ Wt,
                       __half* __restrict__ G, int nrows, int blk,
                       f16 (*xs)[72], f16 (*ws)[72]) {
  const int tid = threadIdx.x;
  const int wave = tid >> 6;
  const int lane = tid & 63;
  const int mrow = lane & 15;
  const int kg = lane >> 4;
  const int row0 = blk * 128;

  f32x4 acc[2][8];
#pragma unroll
  for (int i = 0; i < 2; ++i)
#pragma unroll
    for (int j = 0; j < 8; ++j) acc[i][j] = (f32x4){0.f, 0.f, 0.f, 0.f};

  for (int k0 = 0; k0 < 128; k0 += 64) {
    if constexpr (sizeof(TIN) == 4) {
#pragma unroll
      for (int t = tid; t < 2048; t += 256) {
        int r = t >> 4;
        int kk = (t & 15) * 4;
        float4 v = make_float4(0.f, 0.f, 0.f, 0.f);
        if (row0 + r < nrows)
          v = *(const float4*)((const float*)X + (size_t)(row0 + r) * 128 + k0 + kk);
        f16x4 hv = {(f16)v.x, (f16)v.y, (f16)v.z, (f16)v.w};
        *(f16x4*)&xs[r][kk] = hv;
      }
    } else {
#pragma unroll
      for (int t = tid; t < 1024; t += 256) {
        int r = t >> 3;
        int kk = (t & 7) * 8;
        f16x8 v = (f16x8){0, 0, 0, 0, 0, 0, 0, 0};
        if (row0 + r < nrows)
          v = *(const f16x8*)((const f16*)X + (size_t)(row0 + r) * 128 + k0 + kk);
        *(f16x8*)&xs[r][kk] = v;
      }
    }
#pragma unroll
    for (int t = tid; t < 1024; t += 256) {
      int r = t >> 3;
      int kk = (t & 7) * 8;
      *(f16x8*)&ws[r][kk] =
          *(const f16x8*)((const f16*)Wt + (size_t)r * 128 + k0 + kk);
    }
    __syncthreads();
#pragma unroll
    for (int ks = 0; ks < 64; ks += 32) {
      f16x8 a0 = *(const f16x8*)&xs[wave * 32 + mrow][ks + kg * 8];
      f16x8 a1 = *(const f16x8*)&xs[wave * 32 + 16 + mrow][ks + kg * 8];
#pragma unroll
      for (int nt = 0; nt < 8; ++nt) {
        f16x8 b = *(const f16x8*)&ws[nt * 16 + mrow][ks + kg * 8];
        acc[0][nt] = __builtin_amdgcn_mfma_f32_16x16x32_f16(a0, b, acc[0][nt], 0, 0, 0);
        acc[1][nt] = __builtin_amdgcn_mfma_f32_16x16x32_f16(a1, b, acc[1][nt], 0, 0, 0);
      }
    }
    __syncthreads();
  }
#pragma unroll
  for (int mt = 0; mt < 2; ++mt) {
    int rbase = row0 + wave * 32 + mt * 16 + kg * 4;
#pragma unroll
    for (int i = 0; i < 4; ++i) {
      int grow = rbase + i;
      if (grow < nrows) {
        __half* gp = G + (size_t)grow * 128 + mrow;
#pragma unroll
        for (int nt = 0; nt < 8; ++nt)
          gp[nt * 16] = __float2half_rn(acc[mt][nt][i]);
      }
    }
  }
}

__global__ __launch_bounds__(256)
void mfma_gemm128_kernel(const __half* __restrict__ X, const __half* __restrict__ Wt,
                         __half* __restrict__ G, int nrows) {
  __shared__ f16 xs[128][72];
  __shared__ f16 ws[128][72];
  mfma_gemm128_body<__half>(X, Wt, G, nrows, blockIdx.x, xs, ws);
}

// Fat K2: blocks [0,gGemm) run MFMA gemm layer-0; rest finalize one bucket.
__global__ __launch_bounds__(256)
void gemm128_build_kernel(const float* __restrict__ X, const __half* __restrict__ Wt,
                          __half* __restrict__ G, int nrows, int gGemm,
                          const unsigned* __restrict__ bucketbuf,
                          const int* __restrict__ bucket_cnt,
                          int* __restrict__ rowptr, float* __restrict__ dinv,
                          int* __restrict__ col, int N, int E, int NB) {
  __shared__ char shraw[2 * 128 * 72 * sizeof(f16)];  // 36864 >= sizeof(P2Shared)
  if ((int)blockIdx.x < gGemm) {
    f16 (*xs)[72] = (f16(*)[72])shraw;
    f16 (*ws)[72] = (f16(*)[72])(shraw + 128 * 72 * sizeof(f16));
    mfma_gemm128_body<float>(X, Wt, G, nrows, blockIdx.x, xs, ws);
  } else {
    phase2_body(bucketbuf, bucket_cnt, rowptr, dinv, col, N, E, NB,
                blockIdx.x - gGemm, *(P2Shared*)shraw);
  }
}

// Output layer: N=40 (padded to 48 = 3 n-tiles; Wt2 rows 40..47 zero).
__global__ __launch_bounds__(256)
void mfma_gemm48_kernel(const __half* __restrict__ X, const __half* __restrict__ Wt,
                        __half* __restrict__ G, int nrows) {
  __shared__ f16 xs[128][72];
  __shared__ f16 ws[48][72];
  const int tid = threadIdx.x;
  const int wave = tid >> 6;
  const int lane = tid & 63;
  const int mrow = lane & 15;
  const int kg = lane >> 4;
  const int row0 = blockIdx.x * 128;

  f32x4 acc[2][3];
#pragma unroll
  for (int i = 0; i < 2; ++i)
#pragma unroll
    for (int j = 0; j < 3; ++j) acc[i][j] = (f32x4){0.f, 0.f, 0.f, 0.f};

  for (int k0 = 0; k0 < 128; k0 += 64) {
#pragma unroll
    for (int t = tid; t < 1024; t += 256) {
      int r = t >> 3;
      int kk = (t & 7) * 8;
      f16x8 v = (f16x8){0, 0, 0, 0, 0, 0, 0, 0};
      if (row0 + r < nrows)
        v = *(const f16x8*)((const f16*)X + (size_t)(row0 + r) * 128 + k0 + kk);
      *(f16x8*)&xs[r][kk] = v;
    }
#pragma unroll
    for (int t = tid; t < 384; t += 256) {
      int r = t >> 3;
      int kk = (t & 7) * 8;
      *(f16x8*)&ws[r][kk] =
          *(const f16x8*)((const f16*)Wt + (size_t)r * 128 + k0 + kk);
    }
    __syncthreads();
#pragma unroll
    for (int ks = 0; ks < 64; ks += 32) {
      f16x8 a0 = *(const f16x8*)&xs[wave * 32 + mrow][ks + kg * 8];
      f16x8 a1 = *(const f16x8*)&xs[wave * 32 + 16 + mrow][ks + kg * 8];
#pragma unroll
      for (int nt = 0; nt < 3; ++nt) {
        f16x8 b = *(const f16x8*)&ws[nt * 16 + mrow][ks + kg * 8];
        acc[0][nt] = __builtin_amdgcn_mfma_f32_16x16x32_f16(a0, b, acc[0][nt], 0, 0, 0);
        acc[1][nt] = __builtin_amdgcn_mfma_f32_16x16x32_f16(a1, b, acc[1][nt], 0, 0, 0);
      }
    }
    __syncthreads();
  }
#pragma unroll
  for (int mt = 0; mt < 2; ++mt) {
    int rbase = row0 + wave * 32 + mt * 16 + kg * 4;
#pragma unroll
    for (int i = 0; i < 4; ++i) {
      int grow = rbase + i;
      if (grow < nrows) {
#pragma unroll
        for (int nt = 0; nt < 3; ++nt) {
          int c = nt * 16 + mrow;
          if (c < 40)
            G[(size_t)grow * 40 + c] = __float2half_rn(acc[mt][nt][i]);
        }
      }
    }
  }
}

// M=128 aggregate, 16B/lane. Each gathered row weighted by dinv[col] (fma).
template <bool RELU, typename TOUT>
__global__ __launch_bounds__(256)
void aggregate128_kernel(const __half* __restrict__ G, const int* __restrict__ rowptr,
                         const int* __restrict__ col, const float* __restrict__ dinv,
                         const float* __restrict__ bias, TOUT* __restrict__ out,
                         int n) {
  int wid = threadIdx.x >> 6;
  int lane = threadIdx.x & 63;
  int node = blockIdx.x * 4 + wid;
  if (node >= n) return;

  int sub = lane >> 4;
  int c = lane & 15;
  const float4* g4 = (const float4*)G;  // row stride = 16 float4

  int e = rowptr[node];
  int end = rowptr[node + 1];
  float di = dinv[node];

  float a0 = 0.f, a1 = 0.f, a2 = 0.f, a3 = 0.f,
        a4 = 0.f, a5 = 0.f, a6 = 0.f, a7 = 0.f;

  auto accumw = [&](float4 raw, float w) {
    const __half2* h = (const __half2*)&raw;
    float2 f0 = __half22float2(h[0]);
    float2 f1 = __half22float2(h[1]);
    float2 f2 = __half22float2(h[2]);
    float2 f3 = __half22float2(h[3]);
    a0 = fmaf(w, f0.x, a0); a1 = fmaf(w, f0.y, a1);
    a2 = fmaf(w, f1.x, a2); a3 = fmaf(w, f1.y, a3);
    a4 = fmaf(w, f2.x, a4); a5 = fmaf(w, f2.y, a5);
    a6 = fmaf(w, f3.x, a6); a7 = fmaf(w, f3.y, a7);
  };

  if (sub == 0) accumw(g4[(size_t)node * 16 + c], di);  // self-loop once

  int base = e;
  for (; base + 16 <= end; base += 16) {
    int s0 = col[base + sub];
    int s1 = col[base + sub + 4];
    int s2 = col[base + sub + 8];
    int s3 = col[base + sub + 12];
    float w0 = dinv[s0], w1 = dinv[s1], w2 = dinv[s2], w3 = dinv[s3];
    float4 r0 = g4[(size_t)s0 * 16 + c];
    float4 r1 = g4[(size_t)s1 * 16 + c];
    float4 r2 = g4[(size_t)s2 * 16 + c];
    float4 r3 = g4[(size_t)s3 * 16 + c];
    accumw(r0, w0);
    accumw(r1, w1);
    accumw(r2, w2);
    accumw(r3, w3);
  }
  for (; base + 4 <= end; base += 4) {
    int s0 = col[base + sub];
    accumw(g4[(size_t)s0 * 16 + c], dinv[s0]);
  }
  if (base + sub < end) {
    int s0 = col[base + sub];
    accumw(g4[(size_t)s0 * 16 + c], dinv[s0]);
  }

  a0 += __shfl_xor(a0, 16); a1 += __shfl_xor(a1, 16);
  a2 += __shfl_xor(a2, 16); a3 += __shfl_xor(a3, 16);
  a4 += __shfl_xor(a4, 16); a5 += __shfl_xor(a5, 16);
  a6 += __shfl_xor(a6, 16); a7 += __shfl_xor(a7, 16);
  a0 += __shfl_xor(a0, 32); a1 += __shfl_xor(a1, 32);
  a2 += __shfl_xor(a2, 32); a3 += __shfl_xor(a3, 32);
  a4 += __shfl_xor(a4, 32); a5 += __shfl_xor(a5, 32);
  a6 += __shfl_xor(a6, 32); a7 += __shfl_xor(a7, 32);

  if (sub == 0) {
    const float4* b4 = (const float4*)bias;
    float4 bb0 = b4[c * 2];
    float4 bb1 = b4[c * 2 + 1];
    float o[8] = {di * a0 + bb0.x, di * a1 + bb0.y, di * a2 + bb0.z,
                  di * a3 + bb0.w, di * a4 + bb1.x, di * a5 + bb1.y,
                  di * a6 + bb1.z, di * a7 + bb1.w};
    if (RELU) {
#pragma unroll
      for (int j = 0; j < 8; ++j) o[j] = fmaxf(o[j], 0.f);
    }
    if constexpr (sizeof(TOUT) == 2) {
      union { __half2 h[4]; float4 f; } u;
      u.h[0] = __floats2half2_rn(o[0], o[1]);
      u.h[1] = __floats2half2_rn(o[2], o[3]);
      u.h[2] = __floats2half2_rn(o[4], o[5]);
      u.h[3] = __floats2half2_rn(o[6], o[7]);
      *(float4*)((__half*)out + (size_t)node * 128 + c * 8) = u.f;
    } else {
      float4* op = (float4*)((float*)out + (size_t)node * 128 + c * 8);
      op[0] = make_float4(o[0], o[1], o[2], o[3]);
      op[1] = make_float4(o[4], o[5], o[6], o[7]);
    }
  }
}

// M=40 aggregate, 6-way lane-split; rows weighted by dinv[col].
__global__ __launch_bounds__(256)
void aggregate40_kernel(const __half* __restrict__ G, const int* __restrict__ rowptr,
                        const int* __restrict__ col, const float* __restrict__ dinv,
                        const float* __restrict__ bias, float* __restrict__ out,
                        int n) {
  int wid = threadIdx.x >> 6;
  int lane = threadIdx.x & 63;
  int node = blockIdx.x * 4 + wid;
  if (node >= n) return;

  int sub = lane / 10;
  int c = lane % 10;
  const float2* g2 = (const float2*)G;

  int e = rowptr[node];
  int end = rowptr[node + 1];
  float di = dinv[node];

  float ax = 0.f, ay = 0.f, az = 0.f, aw = 0.f;
  if (sub == 0) {
    float2 raw = g2[(size_t)node * 10 + c];
    float2 f0 = __half22float2(*(const __half2*)&raw.x);
    float2 f1 = __half22float2(*(const __half2*)&raw.y);
    ax = di * f0.x; ay = di * f0.y; az = di * f1.x; aw = di * f1.y;
  }

  if (sub < 6) {
    int i = e + sub;
    for (; i + 11 < end; i += 12) {
      int s0 = col[i];
      int s1 = col[i + 6];
      float w0 = dinv[s0], w1 = dinv[s1];
      float2 r0 = g2[(size_t)s0 * 10 + c];
      float2 r1 = g2[(size_t)s1 * 10 + c];
      float2 f0 = __half22float2(*(const __half2*)&r0.x);
      float2 f1 = __half22float2(*(const __half2*)&r0.y);
      float2 f2 = __half22float2(*(const __half2*)&r1.x);
      float2 f3 = __half22float2(*(const __half2*)&r1.y);
      ax = fmaf(w0, f0.x, fmaf(w1, f2.x, ax));
      ay = fmaf(w0, f0.y, fmaf(w1, f2.y, ay));
      az = fmaf(w0, f1.x, fmaf(w1, f3.x, az));
      aw = fmaf(w0, f1.y, fmaf(w1, f3.y, aw));
    }
    for (; i < end; i += 6) {
      int s0 = col[i];
      float w0 = dinv[s0];
      float2 r0 = g2[(size_t)s0 * 10 + c];
      float2 f0 = __half22float2(*(const __half2*)&r0.x);
      float2 f1 = __half22float2(*(const __half2*)&r0.y);
      ax = fmaf(w0, f0.x, ax); ay = fmaf(w0, f0.y, ay);
      az = fmaf(w0, f1.x, az); aw = fmaf(w0, f1.y, aw);
    }
  }

  float bx = __shfl(ax, lane + 30), by = __shfl(ay, lane + 30),
        bz = __shfl(az, lane + 30), bw = __shfl(aw, lane + 30);
  ax += bx; ay += by; az += bz; aw += bw;
  float c1x = __shfl(ax, lane + 10), c1y = __shfl(ay, lane + 10),
        c1z = __shfl(az, lane + 10), c1w = __shfl(aw, lane + 10);
  float c2x = __shfl(ax, lane + 20), c2y = __shfl(ay, lane + 20),
        c2z = __shfl(az, lane + 20), c2w = __shfl(aw, lane + 20);

  if (sub == 0) {
    float sx = ax + c1x + c2x;
    float sy = ay + c1y + c2y;
    float sz = az + c1z + c2z;
    float sw = aw + c1w + c2w;
    float4 bb = ((const float4*)bias)[c];
    float4 o = make_float4(di * sx + bb.x, di * sy + bb.y, di * sz + bb.z,
                           di * sw + bb.w);
    ((float4*)out)[(size_t)node * 10 + c] = o;
  }
}

extern "C" void kernel_launch(void* const* d_in, const int* in_sizes, int n_in,
                              void* d_out, int out_size, void* d_ws, size_t ws_size,
                              hipStream_t stream) {
  const float* x = (const float*)d_in[0];
  const float* W0 = (const float*)d_in[1];
  const float* b0 = (const float*)d_in[2];
  const float* W1 = (const float*)d_in[3];
  const float* b1 = (const float*)d_in[4];
  const float* W2 = (const float*)d_in[5];
  const float* b2 = (const float*)d_in[6];
  const int* ei = (const int*)d_in[7];

  const int N = in_sizes[0] / 128;
  const int E = in_sizes[7] / 2;
  const int* src = ei;
  const int* dst = ei + E;
  const int NB = (N + 255) >> 8;

  char* w = (char*)d_ws;
  size_t off = 0;
  auto alloc = [&](size_t bytes) -> void* {
    void* p = w + off;
    off = (off + bytes + 255) & ~(size_t)255;
    return p;
  };
  int* bucket_cnt = (int*)alloc((size_t)NBMAX * 4);
  float* dinv = (float*)alloc((size_t)N * 4);
  int* rowptr = (int*)alloc((size_t)(N + 1) * 4);
  int* col = (int*)alloc((size_t)E * 4);
  unsigned* bucketbuf = (unsigned*)alloc((size_t)NB * CAP * 4);
  __half* gbuf = (__half*)alloc((size_t)N * 128 * 2);
  __half* hbuf = (__half*)alloc((size_t)N * 128 * 2);
  __half* w0t = (__half*)alloc(128 * 128 * 2);
  __half* w1t = (__half*)alloc(128 * 128 * 2);
  __half* w2t = (__half*)alloc(48 * 128 * 2);
  (void)ws_size;

  hipMemsetAsync(bucket_cnt, 0, (size_t)NBMAX * 4, stream);

  dim3 blk(256);
  int gP1 = (E + 4095) / 4096;
  int gW = (38912 + 255) / 256;
  int gGemm = (N + 127) / 128;
  int gAgg = (N + 3) / 4;

  // K1: bucket partition + W transpose prep
  bucket_prep_kernel<<<gP1 + gW, blk, 0, stream>>>(src, dst, E, gP1, NB,
                                                   bucket_cnt, bucketbuf,
                                                   W0, W1, W2, w0t, w1t, w2t);
  // K2: MFMA gemm layer-0 (raw h, no dinv) + per-bucket CSR finalize
  gemm128_build_kernel<<<gGemm + NB, blk, 0, stream>>>(x, w0t, gbuf, N, gGemm,
                                                       bucketbuf, bucket_cnt,
                                                       rowptr, dinv, col, N, E, NB);

  aggregate128_kernel<true, __half><<<gAgg, blk, 0, stream>>>(gbuf, rowptr, col, dinv,
                                                              b0, hbuf, N);
  mfma_gemm128_kernel<<<gGemm, blk, 0, stream>>>(hbuf, w1t, gbuf, N);
  aggregate128_kernel<true, __half><<<gAgg, blk, 0, stream>>>(gbuf, rowptr, col, dinv,
                                                              b1, hbuf, N);
  mfma_gemm48_kernel<<<gGemm, blk, 0, stream>>>(hbuf, w2t, gbuf, N);
  aggregate40_kernel<<<gAgg, blk, 0, stream>>>(gbuf, rowptr, col, dinv, b2,
                                               (float*)d_out, N);
}